// Round 8
// baseline (163.577 us; speedup 1.0000x reference)
//
#include <hip/hip_runtime.h>
#include <float.h>

#define CC 256
#define HH 200
#define WW 320
#define HW (HH * WW)
#define MM 14
#define NCH 8            // channels staged per barrier round
#define CG 4             // channel-group blocks per (roi, bin-row)
#define CPB (CC / CG)    // 64 channels per block
#define NR (CPB / NCH)   // 8 rounds
#define SP2 147          // padded col count (cols <= 146); odd -> row stagger
#define SPAN_CAP 146

__global__ void roi_init(float* __restrict__ binmax) {
    int t = blockIdx.x * blockDim.x + threadIdx.x;
    if (t < MM * MM) binmax[t] = -FLT_MAX;
}

__device__ inline void atomicMaxF(float* addr, float val) {
    // Ordered-int trick: valid for finite floats.
    if (val >= 0.0f) {
        atomicMax((int*)addr, __float_as_int(val));
    } else {
        atomicMin((unsigned int*)addr, __float_as_uint(val));
    }
}

// v5 skeleton (fat 8-ch rounds, lockstep raw barriers, T14 issue-early
// prefetch, 19KB LDS -> 8 blocks/CU) with the LDS traffic vectorized:
// layout tile[cs][row][col][ch&1] so
//   - loader writes column-PAIRS per channel -> ds_write2_b32 (2 cols/instr)
//   - compute reads channel-PAIRS per corner -> ds_read(2)_b64 (2 ch/instr,
//     rows ra/rb fused by constant +SP2 offset)
// cutting LDS wave-instructions ~2x (the measured bottleneck pipe).
__global__ __launch_bounds__(256, 8) void roi_reduce(
    const float* __restrict__ feature,
    const float* __restrict__ rois,
    float* __restrict__ binmax)
{
    const int bid = blockIdx.x;
    const int cg  = bid & (CG - 1);
    const int rm  = bid >> 2;          // CG == 4
    const int m   = rm % MM;
    const int r   = rm / MM;
    const int tid = threadIdx.x;
    const int cbase = cg * CPB;

    const float ry1 = rois[r * 4 + 0];
    const float rx1 = rois[r * 4 + 1];
    const float ry2 = rois[r * 4 + 2];
    const float rx2 = rois[r * 4 + 3];
    const float sh = (ry2 - ry1) * (1.0f / 14.0f);
    const float sw = (rx2 - rx1) * (1.0f / 14.0f);
    const float f13 = 1.0f / 3.0f, f23 = 2.0f / 3.0f;

    // Two y sample coords for this bin-row m (reference clamp semantics).
    const float yA = ry1 + sh * (float)m + sh * f13;
    const float yB = ry1 + sh * (float)m + sh * f23;
    const int y1A = min(max((int)floorf(yA), 0), HH - 1);
    const int y2A = min(max((int)floorf(yA) + 1, 0), HH - 1);
    const int y1B = min(max((int)floorf(yB), 0), HH - 1);
    const int y2B = min(max((int)floorf(yB) + 1, 0), HH - 1);
    const float wyloA = yA - (float)y1A, wyhiA = (float)y2A - yA;
    const float wyloB = yB - (float)y1B, wyhiB = (float)y2B - yB;

    // Column window covering all 28 x sample points' corners; even-aligned
    // so float2 global loads are 8B-aligned.
    const float xmin = rx1 + sw * f13;
    const float xmax = rx1 + sw * 13.0f + sw * f23;
    int xlo = min(max((int)floorf(xmin), 0), WW - 1);
    int xhi = min(max((int)floorf(xmax) + 1, 0), WW - 1);
    const int xlo2 = xlo & ~1;
    int span = xhi - xlo2 + 1;
    if (span > SPAN_CAP) span = SPAN_CAP;  // cannot trigger with given input bounds

    // Compute-thread mapping: tid = s + 56*cs ; s = n*4 + j*2 + i
    const int s  = tid % 56;
    const int cs = tid / 56;        // channel-pair plane 0..3 (tid>=224 -> loader-only)
    const int n  = s >> 2;
    const int j  = (s >> 1) & 1;
    const int i  = s & 1;
    const bool active = (tid < 224);

    float wxlo = 0.f, wxhi = 0.f, wylo = 0.f, wyhi = 0.f;
    int idx0 = 0;
    bool csel = false;
    if (active) {
        float x = rx1 + sw * (float)n + sw * (j ? f23 : f13);
        int x1c = min(max((int)floorf(x), 0), WW - 1);
        int x2c = min(max((int)floorf(x) + 1, 0), WW - 1);
        wxlo = x - (float)x1c;
        wxhi = (float)x2c - x;
        int c0 = min(max(x1c - xlo2, 0), span - 1);
        int c1 = min(max(x2c - xlo2, 0), span - 1);
        csel = (c1 == c0);            // right-edge clamp (unreachable here)
        int ra;
        if (i == 0) { ra = 0; wylo = wyloA; wyhi = wyhiA; }
        else        { ra = 2; wylo = wyloB; wyhi = wyhiB; }
        idx0 = (cs * 4 + ra) * SP2 + c0;   // float2 index of (ra, c0)
    }

    // tile[cs:4][row:4][col:SP2][par:2] = 4*4*147*2*4B = 18816 B.
    __shared__ float tile[4 * 4 * SP2 * 2];
    __shared__ float pmax[224];
    const float2* tp = (const float2*)tile;

    // Loader mapping: wave rg owns one feature row; lane owns a column PAIR.
    const int rg   = tid >> 6;
    const int lane = tid & 63;
    const int myrow = (rg == 0) ? y1A : (rg == 1) ? y2A : (rg == 2) ? y1B : y2B;
    const float* srcRow = feature + cbase * HW + myrow * WW + xlo2;

    const int colA = lane * 2;
    const int colB = 128 + lane * 2;
    const bool mA = colA < span;
    const bool mB = colB < span;   // span <= 146 -> lanes 0..8 only

    float2 tA2[NCH], tB2[NCH];

    #define ISSUE(cc) do {                                                     \
        const float* s_ = srcRow + (size_t)(cc) * HW;                          \
        if (mA) { _Pragma("unroll")                                            \
            for (int ch = 0; ch < NCH; ++ch)                                   \
                tA2[ch] = *(const float2*)(s_ + ch * HW + colA); }             \
        if (mB) { _Pragma("unroll")                                            \
            for (int ch = 0; ch < NCH; ++ch)                                   \
                tB2[ch] = *(const float2*)(s_ + ch * HW + colB); }             \
    } while (0)

    ISSUE(0);
    float lmax = -FLT_MAX;

    for (int k = 0; k < NR; ++k) {
        // [A] this round's prefetched regs landed (latency hid under the
        // previous round's compute across 8 resident blocks).
        asm volatile("s_waitcnt vmcnt(0)" ::: "memory");
        // [B] all waves' previous compute done -> tile overwritable.
        __builtin_amdgcn_s_barrier();
        asm volatile("" ::: "memory");

        // [C] registers -> LDS. Per channel: two floats 8B apart
        // (ds_write2_b32 offset0:0 offset1:2).
        if (mA) {
            #pragma unroll
            for (int ch = 0; ch < NCH; ++ch) {
                float* wp = &tile[(((ch >> 1) * 4 + rg) * SP2 + colA) * 2 + (ch & 1)];
                wp[0] = tA2[ch].x;
                wp[2] = tA2[ch].y;
            }
        }
        if (mB) {
            #pragma unroll
            for (int ch = 0; ch < NCH; ++ch) {
                float* wp = &tile[(((ch >> 1) * 4 + rg) * SP2 + colB) * 2 + (ch & 1)];
                wp[0] = tB2[ch].x;
                wp[2] = tB2[ch].y;
            }
        }

        // [D] issue next round's loads NOW (in flight across barrier+compute).
        if (k + 1 < NR) ISSUE((k + 1) * NCH);

        // [E] my LDS writes complete; [F] everyone's writes visible.
        asm volatile("s_waitcnt lgkmcnt(0)" ::: "memory");
        __builtin_amdgcn_s_barrier();
        asm volatile("" ::: "memory");

        // [G] compute: 4 float2 reads give both channels x both corner cols;
        // rows ra/rb are +SP2 apart (fusable to ds_read2_b64).
        if (active) {
            float2 v11 = tp[idx0];
            float2 v12 = tp[idx0 + 1];
            float2 v21 = tp[idx0 + SP2];
            float2 v22 = tp[idx0 + SP2 + 1];
            if (csel) { v12 = v11; v22 = v21; }   // right-edge clamp safety
            float pe = v11.x * wxhi + v12.x * wxlo;
            float qe = v21.x * wxhi + v22.x * wxlo;
            lmax = fmaxf(lmax, pe * wyhi + qe * wylo);
            float po = v11.y * wxhi + v12.y * wxlo;
            float qo = v21.y * wxhi + v22.y * wxlo;
            lmax = fmaxf(lmax, po * wyhi + qo * wylo);
        }
    }
    #undef ISSUE

    if (active) pmax[tid] = lmax;
    __syncthreads();
    if (tid < MM) {  // one thread per bin n
        float v = -FLT_MAX;
        #pragma unroll
        for (int c4 = 0; c4 < 4; ++c4)
            #pragma unroll
            for (int q4 = 0; q4 < 4; ++q4)
                v = fmaxf(v, pmax[c4 * 56 + tid * 4 + q4]);
        atomicMaxF(&binmax[m * MM + tid], v);
    }
}

__global__ __launch_bounds__(256) void roi_bcast(
    const float* __restrict__ binmax, float4* __restrict__ out, int total4)
{
    __shared__ float4 b4[49];  // 196 floats = 49 float4, aligned with bin period
    int t = threadIdx.x;
    if (t < 49) b4[t] = ((const float4*)binmax)[t];
    __syncthreads();
    const int stride = gridDim.x * 256;
    for (int idx = blockIdx.x * 256 + t; idx < total4; idx += stride)
        out[idx] = b4[idx % 49];
}

extern "C" void kernel_launch(void* const* d_in, const int* in_sizes, int n_in,
                              void* d_out, int out_size, void* d_ws, size_t ws_size,
                              hipStream_t stream) {
    const float* feature = (const float*)d_in[0];
    const float* rois    = (const float*)d_in[1];
    float* binmax = (float*)d_ws;
    float* out    = (float*)d_out;

    const int R = in_sizes[1] / 4;

    roi_init<<<1, 256, 0, stream>>>(binmax);
    roi_reduce<<<R * MM * CG, 256, 0, stream>>>(feature, rois, binmax);

    const int total4 = out_size / 4;
    int nb = (total4 + 255) / 256;
    if (nb > 2048) nb = 2048;
    roi_bcast<<<nb, 256, 0, stream>>>(binmax, (float4*)out, total4);
}

// Round 9
// 143.943 us; speedup vs baseline: 1.1364x; 1.1364x over previous
//
#include <hip/hip_runtime.h>
#include <float.h>

#define CC 256
#define HH 200
#define WW 320
#define HW (HH * WW)
#define MM 14
#define CG 4             // channel-group blocks per (roi, bin-row)
#define CPB (CC / CG)    // 64 channels per block
#define KPW 16           // channels per wave (4 waves x 16 = 64)

__global__ void roi_init(float* __restrict__ binmax) {
    int t = blockIdx.x * blockDim.x + threadIdx.x;
    if (t < MM * MM) binmax[t] = -FLT_MAX;
}

__device__ inline void atomicMaxF(float* addr, float val) {
    // Ordered-int trick: valid for finite floats.
    if (val >= 0.0f) {
        atomicMax((int*)addr, __float_as_int(val));
    } else {
        atomicMin((unsigned int*)addr, __float_as_uint(val));
    }
}

// Direct-load roi_reduce: no LDS tile, no loader waves, no main-loop
// barriers. Wave w owns 16 channels exclusively; lane = sample combo
// s = n*4 + j*2 + i. Per channel each lane issues two float2 loads (the
// corner PAIR at x1c, since x2c == x1c+1 for all reachable coords) for
// rows y1/y2 and does the 5-FLOP bilinear + max. L1 provides the reuse
// the LDS tile used to provide (each (ch,row) segment is ~4 cache lines
// read by 28 lanes of the SAME wave, temporally adjacent). This deletes
// the LDS pipe (~90% of v5's cycle budget: ~19K LDS wave-instrs + 5M
// conflict cycles per dispatch) at the cost of ~+0.5K VMEM instrs.
__global__ __launch_bounds__(256, 8) void roi_reduce(
    const float* __restrict__ feature,
    const float* __restrict__ rois,
    float* __restrict__ binmax)
{
    const int bid = blockIdx.x;
    const int cg  = bid & (CG - 1);
    const int rm  = bid >> 2;          // CG == 4
    const int m   = rm % MM;
    const int r   = rm / MM;
    const int tid = threadIdx.x;
    const int w    = tid >> 6;         // wave id 0..3 = channel quarter
    const int lane = tid & 63;
    const int s    = (lane < 56) ? lane : 55;   // lanes 56..63 duplicate 55
    const int cbase = cg * CPB + w * KPW;

    const float ry1 = rois[r * 4 + 0];
    const float rx1 = rois[r * 4 + 1];
    const float ry2 = rois[r * 4 + 2];
    const float rx2 = rois[r * 4 + 3];
    const float sh = (ry2 - ry1) * (1.0f / 14.0f);
    const float sw = (rx2 - rx1) * (1.0f / 14.0f);
    const float f13 = 1.0f / 3.0f, f23 = 2.0f / 3.0f;

    // Sample coords (reference clamp semantics: corners clamped BEFORE
    // weights are computed from them).
    const int nn = s >> 2;
    const int jj = (s >> 1) & 1;
    const int ii = s & 1;

    const float y = ry1 + sh * (float)m + sh * (ii ? f23 : f13);
    const float x = rx1 + sw * (float)nn + sw * (jj ? f23 : f13);

    const int y1c = min(max((int)floorf(y), 0), HH - 1);
    const int y2c = min(max((int)floorf(y) + 1, 0), HH - 1);
    const int x1c = min(max((int)floorf(x), 0), WW - 1);
    const int x2c = min(max((int)floorf(x) + 1, 0), WW - 1);
    const float wylo = y - (float)y1c, wyhi = (float)y2c - y;
    const float wxlo = x - (float)x1c, wxhi = (float)x2c - x;
    // For the given ROI bounds x2c == x1c+1 always (xmax <= ~302 < 319),
    // so the corner pair [x1c, x1c+1] is one float2 load. (If the clamp
    // ever fired, x2c==x1c and wxlo==x-x1c with wxhi==x1c-x would still
    // be what the reference computes; the .y lane of the pair is then
    // weighted by wxlo = x-x1c and .x by wxhi -- we guard with csel.)
    const bool csel = (x2c == x1c);   // unreachable here; safety only

    typedef float f2v __attribute__((ext_vector_type(2)));
    typedef f2v __attribute__((aligned(4))) f2u;   // 4B-aligned float2 load

    const float* pA = feature + (size_t)cbase * HW + y1c * WW + x1c;
    const float* pB = feature + (size_t)cbase * HW + y2c * WW + x1c;

    float lmax = -FLT_MAX;

    #pragma unroll 4
    for (int kk = 0; kk < KPW; ++kk) {
        f2v a = *(const f2u*)pA;
        f2v b = *(const f2u*)pB;
        pA += HW;
        pB += HW;
        float ax2 = csel ? a.x : a.y;
        float bx2 = csel ? b.x : b.y;
        float p = a.x * wxhi + ax2 * wxlo;
        float q = b.x * wxhi + bx2 * wxlo;
        lmax = fmaxf(lmax, p * wyhi + q * wylo);
    }

    __shared__ float pmax[224];
    if (lane < 56) pmax[w * 56 + s] = lmax;
    __syncthreads();
    if (tid < MM) {  // one thread per bin n
        float v = -FLT_MAX;
        #pragma unroll
        for (int c4 = 0; c4 < 4; ++c4)
            #pragma unroll
            for (int q4 = 0; q4 < 4; ++q4)
                v = fmaxf(v, pmax[c4 * 56 + tid * 4 + q4]);
        atomicMaxF(&binmax[m * MM + tid], v);
    }
}

__global__ __launch_bounds__(256) void roi_bcast(
    const float* __restrict__ binmax, float4* __restrict__ out, int total4)
{
    __shared__ float4 b4[49];  // 196 floats = 49 float4, aligned with bin period
    int t = threadIdx.x;
    if (t < 49) b4[t] = ((const float4*)binmax)[t];
    __syncthreads();
    const int stride = gridDim.x * 256;
    for (int idx = blockIdx.x * 256 + t; idx < total4; idx += stride)
        out[idx] = b4[idx % 49];
}

extern "C" void kernel_launch(void* const* d_in, const int* in_sizes, int n_in,
                              void* d_out, int out_size, void* d_ws, size_t ws_size,
                              hipStream_t stream) {
    const float* feature = (const float*)d_in[0];
    const float* rois    = (const float*)d_in[1];
    float* binmax = (float*)d_ws;
    float* out    = (float*)d_out;

    const int R = in_sizes[1] / 4;

    roi_init<<<1, 256, 0, stream>>>(binmax);
    roi_reduce<<<R * MM * CG, 256, 0, stream>>>(feature, rois, binmax);

    const int total4 = out_size / 4;
    int nb = (total4 + 255) / 256;
    if (nb > 2048) nb = 2048;
    roi_bcast<<<nb, 256, 0, stream>>>(binmax, (float4*)out, total4);
}

// Round 10
// 139.556 us; speedup vs baseline: 1.1721x; 1.0314x over previous
//
#include <hip/hip_runtime.h>
#include <float.h>

#define CC 256
#define HH 200
#define WW 320
#define HW (HH * WW)
#define MM 14
#define CG 4             // channel-group blocks per (roi, bin-row)
#define CPB (CC / CG)    // 64 channels per block
#define KPW 16           // channels per wave (4 waves x 16 = 64)

__global__ void roi_init(float* __restrict__ binmax) {
    int t = blockIdx.x * blockDim.x + threadIdx.x;
    if (t < MM * MM) binmax[t] = -FLT_MAX;
}

__device__ inline void atomicMaxF(float* addr, float val) {
    // Ordered-int trick: valid for finite floats.
    if (val >= 0.0f) {
        atomicMax((int*)addr, __float_as_int(val));
    } else {
        atomicMin((unsigned int*)addr, __float_as_uint(val));
    }
}

// v7 (direct-load, no LDS tile, no main-loop barriers) with ONE change:
// lane order. v7 used s = n*4 + j*2 + i -- the row-select bit i was the
// FASTEST lane bit, so adjacent lanes alternated rows and the TA coalescer
// saw ~50+ address segments per load (measured ~38 cy/VMEM instr).
// Now s' = i*28 + j*14 + n: lanes 0..27 walk row y1A with x monotone
// per 14-lane run, lanes 28..55 walk row y1B -- consecutive lanes share
// cache lines, so segments merge. Tests the order-sensitivity of the TA
// coalescer with everything else held fixed.
__global__ __launch_bounds__(256, 8) void roi_reduce(
    const float* __restrict__ feature,
    const float* __restrict__ rois,
    float* __restrict__ binmax)
{
    const int bid = blockIdx.x;
    const int cg  = bid & (CG - 1);
    const int rm  = bid >> 2;          // CG == 4
    const int m   = rm % MM;
    const int r   = rm / MM;
    const int tid = threadIdx.x;
    const int w    = tid >> 6;         // wave id 0..3 = channel quarter
    const int lane = tid & 63;
    const int s    = (lane < 56) ? lane : 55;   // lanes 56..63 duplicate 55
    const int cbase = cg * CPB + w * KPW;

    const float ry1 = rois[r * 4 + 0];
    const float rx1 = rois[r * 4 + 1];
    const float ry2 = rois[r * 4 + 2];
    const float rx2 = rois[r * 4 + 3];
    const float sh = (ry2 - ry1) * (1.0f / 14.0f);
    const float sw = (rx2 - rx1) * (1.0f / 14.0f);
    const float f13 = 1.0f / 3.0f, f23 = 2.0f / 3.0f;

    // Lane decomposition: s = ii*28 + jj*14 + nn  (nn fastest -> x-adjacent
    // lanes are address-adjacent; row changes only at the half-wave point).
    const int nn = s % 14;
    const int jj = (s / 14) & 1;
    const int ii = s / 28;

    // Sample coords (reference clamp semantics: corners clamped BEFORE
    // weights are computed from them).
    const float y = ry1 + sh * (float)m + sh * (ii ? f23 : f13);
    const float x = rx1 + sw * (float)nn + sw * (jj ? f23 : f13);

    const int y1c = min(max((int)floorf(y), 0), HH - 1);
    const int y2c = min(max((int)floorf(y) + 1, 0), HH - 1);
    const int x1c = min(max((int)floorf(x), 0), WW - 1);
    const int x2c = min(max((int)floorf(x) + 1, 0), WW - 1);
    const float wylo = y - (float)y1c, wyhi = (float)y2c - y;
    const float wxlo = x - (float)x1c, wxhi = (float)x2c - x;
    // x2c == x1c+1 for all reachable coords (xmax < 319), so the corner
    // pair [x1c, x1c+1] is one float2 load; csel guards the (unreachable)
    // right-edge clamp case.
    const bool csel = (x2c == x1c);

    typedef float f2v __attribute__((ext_vector_type(2)));
    typedef f2v __attribute__((aligned(4))) f2u;   // 4B-aligned float2 load

    const float* pA = feature + (size_t)cbase * HW + y1c * WW + x1c;
    const float* pB = feature + (size_t)cbase * HW + y2c * WW + x1c;

    float lmax = -FLT_MAX;

    #pragma unroll 4
    for (int kk = 0; kk < KPW; ++kk) {
        f2v a = *(const f2u*)pA;
        f2v b = *(const f2u*)pB;
        pA += HW;
        pB += HW;
        float ax2 = csel ? a.x : a.y;
        float bx2 = csel ? b.x : b.y;
        float p = a.x * wxhi + ax2 * wxlo;
        float q = b.x * wxhi + bx2 * wxlo;
        lmax = fmaxf(lmax, p * wyhi + q * wylo);
    }

    __shared__ float pmax[224];
    if (lane < 56) pmax[w * 56 + s] = lmax;
    __syncthreads();
    if (tid < MM) {  // one thread per bin n; samples at s' = t*14 + n
        float v = -FLT_MAX;
        #pragma unroll
        for (int c4 = 0; c4 < 4; ++c4)
            #pragma unroll
            for (int t4 = 0; t4 < 4; ++t4)
                v = fmaxf(v, pmax[c4 * 56 + t4 * 14 + tid]);
        atomicMaxF(&binmax[m * MM + tid], v);
    }
}

__global__ __launch_bounds__(256) void roi_bcast(
    const float* __restrict__ binmax, float4* __restrict__ out, int total4)
{
    __shared__ float4 b4[49];  // 196 floats = 49 float4, aligned with bin period
    int t = threadIdx.x;
    if (t < 49) b4[t] = ((const float4*)binmax)[t];
    __syncthreads();
    const int stride = gridDim.x * 256;
    for (int idx = blockIdx.x * 256 + t; idx < total4; idx += stride)
        out[idx] = b4[idx % 49];
}

extern "C" void kernel_launch(void* const* d_in, const int* in_sizes, int n_in,
                              void* d_out, int out_size, void* d_ws, size_t ws_size,
                              hipStream_t stream) {
    const float* feature = (const float*)d_in[0];
    const float* rois    = (const float*)d_in[1];
    float* binmax = (float*)d_ws;
    float* out    = (float*)d_out;

    const int R = in_sizes[1] / 4;

    roi_init<<<1, 256, 0, stream>>>(binmax);
    roi_reduce<<<R * MM * CG, 256, 0, stream>>>(feature, rois, binmax);

    const int total4 = out_size / 4;
    int nb = (total4 + 255) / 256;
    if (nb > 2048) nb = 2048;
    roi_bcast<<<nb, 256, 0, stream>>>(binmax, (float4*)out, total4);
}

// Round 11
// 139.460 us; speedup vs baseline: 1.1729x; 1.0007x over previous
//
#include <hip/hip_runtime.h>
#include <float.h>

#define CC 256
#define HH 200
#define WW 320
#define HW (HH * WW)
#define MM 14
#define CG 4             // channel-group blocks per (roi, bin-row)
#define CPB (CC / CG)    // 64 channels per block
#define KPW 16           // channels per wave (4 waves x 16 = 64)

__global__ void roi_init(float* __restrict__ binmax) {
    int t = blockIdx.x * blockDim.x + threadIdx.x;
    if (t < MM * MM) binmax[t] = -FLT_MAX;
}

__device__ inline void atomicMaxF(float* addr, float val) {
    // Ordered-int trick: valid for finite floats.
    if (val >= 0.0f) {
        atomicMax((int*)addr, __float_as_int(val));
    } else {
        atomicMin((unsigned int*)addr, __float_as_uint(val));
    }
}

// v8 (direct-load, no LDS tile, no main-loop barriers) with the lane order
// completed: s = ii*28 + nn*2 + jj. v8's s = ii*28 + jj*14 + nn made rows
// contiguous (57.5 -> 50.0 us) but walked each row's x-range TWICE (j=0 run
// then j=1 run), doubling the consecutive-lane segment count. Sorting by x
// (nn*2 + jj: strictly monotone within each 28-lane row-half, adjacent
// lanes ~sw/3 px apart) collapses each half to its minimal cache-line
// cover (~4-7 lines), targeting the ~10-14 segment floor per VMEM instr
// (measured 33 cy/instr at ~2x that).
__global__ __launch_bounds__(256, 8) void roi_reduce(
    const float* __restrict__ feature,
    const float* __restrict__ rois,
    float* __restrict__ binmax)
{
    const int bid = blockIdx.x;
    const int cg  = bid & (CG - 1);
    const int rm  = bid >> 2;          // CG == 4
    const int m   = rm % MM;
    const int r   = rm / MM;
    const int tid = threadIdx.x;
    const int w    = tid >> 6;         // wave id 0..3 = channel quarter
    const int lane = tid & 63;
    const int s    = (lane < 56) ? lane : 55;   // lanes 56..63 duplicate 55
    const int cbase = cg * CPB + w * KPW;

    const float ry1 = rois[r * 4 + 0];
    const float rx1 = rois[r * 4 + 1];
    const float ry2 = rois[r * 4 + 2];
    const float rx2 = rois[r * 4 + 3];
    const float sh = (ry2 - ry1) * (1.0f / 14.0f);
    const float sw = (rx2 - rx1) * (1.0f / 14.0f);
    const float f13 = 1.0f / 3.0f, f23 = 2.0f / 3.0f;

    // Lane decomposition: s = ii*28 + nn*2 + jj  (x monotone across each
    // 28-lane row-half; row changes only at the half-wave boundary).
    const int ii  = s / 28;
    const int rem = s % 28;
    const int nn  = rem >> 1;
    const int jj  = rem & 1;

    // Sample coords (reference clamp semantics: corners clamped BEFORE
    // weights are computed from them).
    const float y = ry1 + sh * (float)m + sh * (ii ? f23 : f13);
    const float x = rx1 + sw * (float)nn + sw * (jj ? f23 : f13);

    const int y1c = min(max((int)floorf(y), 0), HH - 1);
    const int y2c = min(max((int)floorf(y) + 1, 0), HH - 1);
    const int x1c = min(max((int)floorf(x), 0), WW - 1);
    const int x2c = min(max((int)floorf(x) + 1, 0), WW - 1);
    const float wylo = y - (float)y1c, wyhi = (float)y2c - y;
    const float wxlo = x - (float)x1c, wxhi = (float)x2c - x;
    // x2c == x1c+1 for all reachable coords (xmax < 319), so the corner
    // pair [x1c, x1c+1] is one float2 load; csel guards the (unreachable)
    // right-edge clamp case.
    const bool csel = (x2c == x1c);

    typedef float f2v __attribute__((ext_vector_type(2)));
    typedef f2v __attribute__((aligned(4))) f2u;   // 4B-aligned float2 load

    const float* pA = feature + (size_t)cbase * HW + y1c * WW + x1c;
    const float* pB = feature + (size_t)cbase * HW + y2c * WW + x1c;

    float lmax = -FLT_MAX;

    #pragma unroll 4
    for (int kk = 0; kk < KPW; ++kk) {
        f2v a = *(const f2u*)pA;
        f2v b = *(const f2u*)pB;
        pA += HW;
        pB += HW;
        float ax2 = csel ? a.x : a.y;
        float bx2 = csel ? b.x : b.y;
        float p = a.x * wxhi + ax2 * wxlo;
        float q = b.x * wxhi + bx2 * wxlo;
        lmax = fmaxf(lmax, p * wyhi + q * wylo);
    }

    __shared__ float pmax[224];
    if (lane < 56) pmax[w * 56 + s] = lmax;
    __syncthreads();
    if (tid < MM) {  // one thread per bin n; partials at ii*28 + n*2 + jj
        float v = -FLT_MAX;
        #pragma unroll
        for (int c4 = 0; c4 < 4; ++c4) {
            const float* pw = &pmax[c4 * 56 + tid * 2];
            v = fmaxf(v, fmaxf(fmaxf(pw[0], pw[1]), fmaxf(pw[28], pw[29])));
        }
        atomicMaxF(&binmax[m * MM + tid], v);
    }
}

__global__ __launch_bounds__(256) void roi_bcast(
    const float* __restrict__ binmax, float4* __restrict__ out, int total4)
{
    __shared__ float4 b4[49];  // 196 floats = 49 float4, aligned with bin period
    int t = threadIdx.x;
    if (t < 49) b4[t] = ((const float4*)binmax)[t];
    __syncthreads();
    const int stride = gridDim.x * 256;
    for (int idx = blockIdx.x * 256 + t; idx < total4; idx += stride)
        out[idx] = b4[idx % 49];
}

extern "C" void kernel_launch(void* const* d_in, const int* in_sizes, int n_in,
                              void* d_out, int out_size, void* d_ws, size_t ws_size,
                              hipStream_t stream) {
    const float* feature = (const float*)d_in[0];
    const float* rois    = (const float*)d_in[1];
    float* binmax = (float*)d_ws;
    float* out    = (float*)d_out;

    const int R = in_sizes[1] / 4;

    roi_init<<<1, 256, 0, stream>>>(binmax);
    roi_reduce<<<R * MM * CG, 256, 0, stream>>>(feature, rois, binmax);

    const int total4 = out_size / 4;
    int nb = (total4 + 255) / 256;
    if (nb > 2048) nb = 2048;
    roi_bcast<<<nb, 256, 0, stream>>>(binmax, (float4*)out, total4);
}

// Round 13
// 138.215 us; speedup vs baseline: 1.1835x; 1.0090x over previous
//
#include <hip/hip_runtime.h>
#include <float.h>

#define CC 256
#define HH 200
#define WW 320
#define HW (HH * WW)
#define MM 14
#define NCH 8              // channels staged per barrier round
#define CG 4               // channel-group blocks per (roi, bin-row)
#define CPB (CC / CG)      // 64 channels per block
#define NR (CPB / NCH)     // 8 rounds
#define SPF 152            // floats per (ch,row) slice: 608B, 16B-aligned
#define NSLICE (NCH * 4)   // 32 slices per round
#define MAXSLOT 5          // ceil(32*37/256)

__global__ void roi_init(float* __restrict__ binmax) {
    int t = blockIdx.x * blockDim.x + threadIdx.x;
    if (t < MM * MM) binmax[t] = -FLT_MAX;
}

__device__ inline void atomicMaxF(float* addr, float val) {
    // Ordered-int trick: valid for finite floats.
    if (val >= 0.0f) {
        atomicMax((int*)addr, __float_as_int(val));
    } else {
        atomicMin((unsigned int*)addr, __float_as_uint(val));
    }
}

// v10: coalesced-staged redistribute. v7-v9 established the divergent-gather
// floor: ~33 cy/VMEM instr (2 lanes/cy TA processing), order-insensitive ->
// 118K cy/CU. This version converts those gathers into (a) PACKED full-wave
// float4 staging loads (all 256 threads cover the 32 (ch,row) slices x span4
// col-groups of a round; near-coalesced ~6cy) + ds_write_b128 (consecutive
// 16B -> bank-tiled, conflict-free), and (b) fused LDS reads: linear
// [slice][152] layout puts a thread's two rows 152 dwords apart ->
// ds_read2_b32 (offset1=152/153), 4 dual-dword reads/thread/round.
// Skeleton is v5's proven one: fat NCH=8 rounds, raw-barrier lockstep
// (preserves L2 locality), T14 issue-early prefetch, 8 blocks/CU.
__global__ __launch_bounds__(256, 8) void roi_reduce(
    const float* __restrict__ feature,
    const float* __restrict__ rois,
    float* __restrict__ binmax)
{
    const int bid = blockIdx.x;
    const int cg  = bid & (CG - 1);
    const int rm  = bid >> 2;          // CG == 4
    const int m   = rm % MM;
    const int r   = rm / MM;
    const int tid = threadIdx.x;
    const int cbase = cg * CPB;

    const float ry1 = rois[r * 4 + 0];
    const float rx1 = rois[r * 4 + 1];
    const float ry2 = rois[r * 4 + 2];
    const float rx2 = rois[r * 4 + 3];
    const float sh = (ry2 - ry1) * (1.0f / 14.0f);
    const float sw = (rx2 - rx1) * (1.0f / 14.0f);
    const float f13 = 1.0f / 3.0f, f23 = 2.0f / 3.0f;

    // Two y sample coords for this bin-row m (reference clamp semantics).
    const float yA = ry1 + sh * (float)m + sh * f13;
    const float yB = ry1 + sh * (float)m + sh * f23;
    const int y1A = min(max((int)floorf(yA), 0), HH - 1);
    const int y2A = min(max((int)floorf(yA) + 1, 0), HH - 1);
    const int y1B = min(max((int)floorf(yB), 0), HH - 1);
    const int y2B = min(max((int)floorf(yB) + 1, 0), HH - 1);
    const float wyloA = yA - (float)y1A, wyhiA = (float)y2A - yA;
    const float wyloB = yB - (float)y1B, wyhiB = (float)y2B - yB;

    // Column window covering all 28 x sample points' corners, 16B-aligned.
    const float xmin = rx1 + sw * f13;
    const float xmax = rx1 + sw * 13.0f + sw * f23;
    int xlo = min(max((int)floorf(xmin), 0), WW - 1);
    int xhi = min(max((int)floorf(xmax) + 1, 0), WW - 1);
    const int xlo4 = xlo & ~3;
    int span = xhi - xlo4 + 1;
    if (span > 4 * 37 - 3) span = 4 * 37 - 3;  // span<=145 (cannot trigger)
    const int span4 = (span + 3) >> 2;         // <= 37

    // Compute-thread mapping (v5): tid = s + 56*cs ; s = n*4 + j*2 + i
    const int s  = tid % 56;
    const int cs = tid / 56;        // channel-pair group 0..3 (tid>=224 loader-only)
    const int n  = s >> 2;
    const int j  = (s >> 1) & 1;
    const int i  = s & 1;
    const bool active = (tid < 224);

    float wxlo = 0.f, wxhi = 0.f, wylo = 0.f, wyhi = 0.f;
    int aoff0 = 0, aoff1 = 0;
    bool csel = false;
    if (active) {
        float x = rx1 + sw * (float)n + sw * (j ? f23 : f13);
        int x1c = min(max((int)floorf(x), 0), WW - 1);
        int x2c = min(max((int)floorf(x) + 1, 0), WW - 1);
        wxlo = x - (float)x1c;
        wxhi = (float)x2c - x;
        int c0 = min(max(x1c - xlo4, 0), span - 1);
        csel = (x2c == x1c);           // right-edge clamp (unreachable here)
        int ra;
        if (i == 0) { ra = 0; wylo = wyloA; wyhi = wyhiA; }
        else        { ra = 2; wylo = wyloB; wyhi = wyhiB; }
        const int ch0 = cs * 2;
        aoff0 = (ch0 * 4 + ra) * SPF + c0;   // rows ra/ra+1 are +SPF apart
        aoff1 = aoff0 + 4 * SPF;             // channel ch0+1
    }

    __shared__ float tile[NSLICE * SPF];   // 4864 floats = 19456 B
    __shared__ float pmax[224];

    // --- Packed staging slot precompute (once) ---
    const int o0 = y1A * WW, o1 = y2A * WW, o2 = y1B * WW, o3 = y2B * WW;
    const int T = NSLICE * span4;          // total float4 tasks per round
    const char* fbase = (const char*)(feature + (size_t)cbase * HW);

    unsigned gvoff[MAXSLOT];   // byte offset within round-0 channel block
    int      loff[MAXSLOT];    // float index into tile
    bool     val[MAXSLOT];
    #pragma unroll
    for (int q = 0; q < MAXSLOT; ++q) {
        int t = tid + 256 * q;
        bool v = (t < T);
        val[q] = v;
        int tt = v ? t : 0;
        int slice = tt / span4;            // one-time runtime div
        int c4    = tt - slice * span4;
        int ch    = slice >> 2;
        int row   = slice & 3;
        int rowoff = o0;
        rowoff = (row == 1) ? o1 : rowoff;
        rowoff = (row == 2) ? o2 : rowoff;
        rowoff = (row == 3) ? o3 : rowoff;
        gvoff[q] = (unsigned)((ch * HW + rowoff + xlo4 + c4 * 4) * 4);
        loff[q]  = slice * SPF + c4 * 4;   // 16B-aligned (SPF%4==0)
    }

    typedef float f4v __attribute__((ext_vector_type(4)));
    f4v d[MAXSLOT];

    #define ISSUE(kk) do {                                                   \
        const char* fb_ = fbase + (size_t)(kk) * NCH * HW * 4;               \
        _Pragma("unroll")                                                    \
        for (int q = 0; q < MAXSLOT; ++q)                                    \
            if (val[q]) d[q] = *(const f4v*)(fb_ + gvoff[q]);                \
    } while (0)

    ISSUE(0);
    float lmax = -FLT_MAX;

    for (int k = 0; k < NR; ++k) {
        // [A] prefetched regs landed (issued one round ago; latency hid
        // under previous round's compute across 8 resident blocks).
        asm volatile("s_waitcnt vmcnt(0)" ::: "memory");
        // [B] everyone's reads of the previous tile done -> overwritable.
        __builtin_amdgcn_s_barrier();
        asm volatile("" ::: "memory");

        // [C] regs -> LDS: ds_write_b128, consecutive threads write
        // consecutive 16B -> banks tile perfectly (conflict-free).
        #pragma unroll
        for (int q = 0; q < MAXSLOT; ++q)
            if (val[q]) *(f4v*)&tile[loff[q]] = d[q];

        // [D] issue next round's loads NOW (in flight across barrier+compute).
        if (k + 1 < NR) ISSUE(k + 1);

        // [E] my writes complete; [F] all writes visible.
        asm volatile("s_waitcnt lgkmcnt(0)" ::: "memory");
        __builtin_amdgcn_s_barrier();
        asm volatile("" ::: "memory");

        // [G] compute: per channel one ds_read2_b32 pair per corner column
        // ({a[0],a[SPF]} and {a[1],a[SPF+1]} -> offset1 = 152/153).
        if (active) {
            {
                const float* a = &tile[aoff0];
                float v11 = a[0], v21 = a[SPF];
                float v12 = a[1], v22 = a[SPF + 1];
                if (csel) { v12 = v11; v22 = v21; }
                float p  = v11 * wxhi + v12 * wxlo;
                float qq = v21 * wxhi + v22 * wxlo;
                lmax = fmaxf(lmax, p * wyhi + qq * wylo);
            }
            {
                const float* a = &tile[aoff1];
                float v11 = a[0], v21 = a[SPF];
                float v12 = a[1], v22 = a[SPF + 1];
                if (csel) { v12 = v11; v22 = v21; }
                float p  = v11 * wxhi + v12 * wxlo;
                float qq = v21 * wxhi + v22 * wxlo;
                lmax = fmaxf(lmax, p * wyhi + qq * wylo);
            }
        }
    }
    #undef ISSUE

    if (active) pmax[tid] = lmax;
    __syncthreads();
    if (tid < MM) {  // one thread per bin n (s = n*4 + j*2 + i)
        float v = -FLT_MAX;
        #pragma unroll
        for (int c4 = 0; c4 < 4; ++c4)
            #pragma unroll
            for (int q4 = 0; q4 < 4; ++q4)
                v = fmaxf(v, pmax[c4 * 56 + tid * 4 + q4]);
        atomicMaxF(&binmax[m * MM + tid], v);
    }
}

__global__ __launch_bounds__(256) void roi_bcast(
    const float* __restrict__ binmax, float4* __restrict__ out, int total4)
{
    __shared__ float4 b4[49];  // 196 floats = 49 float4, aligned with bin period
    int t = threadIdx.x;
    if (t < 49) b4[t] = ((const float4*)binmax)[t];
    __syncthreads();
    const int stride = gridDim.x * 256;
    for (int idx = blockIdx.x * 256 + t; idx < total4; idx += stride)
        out[idx] = b4[idx % 49];
}

extern "C" void kernel_launch(void* const* d_in, const int* in_sizes, int n_in,
                              void* d_out, int out_size, void* d_ws, size_t ws_size,
                              hipStream_t stream) {
    const float* feature = (const float*)d_in[0];
    const float* rois    = (const float*)d_in[1];
    float* binmax = (float*)d_ws;
    float* out    = (float*)d_out;

    const int R = in_sizes[1] / 4;

    roi_init<<<1, 256, 0, stream>>>(binmax);
    roi_reduce<<<R * MM * CG, 256, 0, stream>>>(feature, rois, binmax);

    const int total4 = out_size / 4;
    int nb = (total4 + 255) / 256;
    if (nb > 2048) nb = 2048;
    roi_bcast<<<nb, 256, 0, stream>>>(binmax, (float4*)out, total4);
}